// Round 3
// baseline (79.212 us; speedup 1.0000x reference)
//
#include <hip/hip_runtime.h>

// LocNet2d on MFMA fp16: 3 locally-connected blocks + linear head.
// L1: per-patch GEMM (64 patches, M=128,N=512,K=48 pad 64) -> A2 fp16 [s][b][k2=o*16+g]
// L2: per-s GEMM M=128,N=512,K=8192, splitK=nkc2 -> P2 fp32 -> reduce -> A3 fp16 [b][o*4+s]
// L3: GEMM M=128,N=512,K=2048, splitK=nkc3 -> P3 fp32 -> fused reduce+head -> out
// gemm blocks: 64x64 tile, 4 waves (2x2 of 32x32), reg-staged prefetch double-buffer.

typedef _Float16 f16;
typedef _Float16 half8 __attribute__((ext_vector_type(8)));
typedef _Float16 half4 __attribute__((ext_vector_type(4)));
typedef float f32x4 __attribute__((ext_vector_type(4)));

// LDS half-index swizzle: rows are 64 halves (128 B); XOR bits 3-5 with row&7
// spreads the 8 16-B slots across banks (G4 fix for 128-B-stride conflicts).
#define SWZ(r, c) ((((r) << 6) + (c)) ^ (((r) & 7) << 3))

__global__ __launch_bounds__(256) void l1_mfma(const float* __restrict__ x,
                                               const float* __restrict__ w1,
                                               f16* __restrict__ A2) {
  // grid: (64 patches pq, 8 o-tiles). Block: 256 thr = 4 waves, tile 128b x 64o.
  const int pq = blockIdx.x, p1 = pq >> 3, q1 = pq & 7;
  const int o0 = blockIdx.y << 6;
  __shared__ __align__(16) f16 Xs[128 * 64];
  __shared__ __align__(16) f16 Ws[64 * 64];
  const int t = threadIdx.x;
#pragma unroll
  for (int i = 0; i < 8; ++i) {
    int idx = (i << 8) + t, row = idx >> 4, j = idx & 15;
    half4 h = {0, 0, 0, 0};
    if (j < 12) {
      float4 v = *(const float4*)(x + ((size_t)row * 3 + (j >> 2)) * 1024 +
                                  (p1 * 4 + (j & 3)) * 32 + q1 * 4);
      h[0] = (f16)v.x; h[1] = (f16)v.y; h[2] = (f16)v.z; h[3] = (f16)v.w;
    }
    *(half4*)&Xs[SWZ(row, j << 2)] = h;
  }
#pragma unroll
  for (int i = 0; i < 4; ++i) {
    int idx = (i << 8) + t, row = idx >> 4, j = idx & 15;
    half4 h = {0, 0, 0, 0};
    if (j < 12) {
      float4 v = *(const float4*)(w1 + (size_t)(o0 + row) * 3072 + (j >> 2) * 1024 +
                                  p1 * 128 + q1 * 16 + (j & 3) * 4);
      h[0] = (f16)v.x; h[1] = (f16)v.y; h[2] = (f16)v.z; h[3] = (f16)v.w;
    }
    *(half4*)&Ws[SWZ(row, j << 2)] = h;
  }
  __syncthreads();
  const int w = t >> 6, lane = t & 63;
  const int wr = w >> 1, wc = w & 1;
  const int frow = lane & 15, fk = (lane >> 4) << 3;
  f32x4 acc[4][2] = {};
#pragma unroll
  for (int ks = 0; ks < 2; ++ks) {
    const int col = (ks << 5) + fk;
    half8 a[4], b[2];
#pragma unroll
    for (int mi = 0; mi < 4; ++mi)
      a[mi] = *(const half8*)&Xs[SWZ(wr * 64 + mi * 16 + frow, col)];
#pragma unroll
    for (int ni = 0; ni < 2; ++ni)
      b[ni] = *(const half8*)&Ws[SWZ(wc * 32 + ni * 16 + frow, col)];
#pragma unroll
    for (int mi = 0; mi < 4; ++mi)
#pragma unroll
      for (int ni = 0; ni < 2; ++ni)
        acc[mi][ni] = __builtin_amdgcn_mfma_f32_16x16x32_f16(a[mi], b[ni], acc[mi][ni], 0, 0, 0);
  }
  const int s2 = ((p1 >> 2) << 1) + (q1 >> 2);
  const int g = ((p1 & 3) << 2) + (q1 & 3);
  f16* A2b = A2 + (size_t)s2 * 128 * 8192;
#pragma unroll
  for (int mi = 0; mi < 4; ++mi)
#pragma unroll
    for (int ni = 0; ni < 2; ++ni)
#pragma unroll
      for (int r = 0; r < 4; ++r) {
        int gm = wr * 64 + mi * 16 + (lane >> 4) * 4 + r;
        int go = o0 + wc * 32 + ni * 16 + (lane & 15);
        float v = fmaxf(acc[mi][ni][r] * 0.14433756729740643f, 0.f);  // 1/sqrt(48)
        A2b[(size_t)gm * 8192 + go * 16 + g] = (f16)v;
      }
}

template <int MODE>  // 0: L2 (w2 gather), 1: L3 (contiguous w3)
__global__ __launch_bounds__(256) void gemm_f16(const f16* __restrict__ A,
                                                const float* __restrict__ W,
                                                float* __restrict__ P,
                                                int iters) {
  __shared__ __align__(16) f16 As[64 * 64];
  __shared__ __align__(16) f16 Bs[64 * 64];
  const int t = threadIdx.x;
  const int bid = blockIdx.x;
  constexpr int AK = (MODE == 0) ? 8192 : 2048;
  constexpr int SROW = (MODE == 0) ? 32768 : 2048;
  const int n = bid & 7, m = (bid >> 3) & 1;
  const int s = (MODE == 0) ? ((bid >> 4) & 3) : 0;
  const int kc = (MODE == 0) ? (bid >> 6) : (bid >> 4);
  const int kbase = kc * (iters << 6);
  const int poff = (MODE == 0) ? (((s >> 1) << 5) + ((s & 1) << 4)) : 0;  // p*32+q*16
  const f16* Ab = A + ((size_t)((MODE == 0 ? s * 128 : 0) + m * 64)) * AK + kbase;
  const int o0 = n << 6;

  // per-thread staging coords (fixed)
  const int ar0 = t >> 3, asl = (t & 7) << 3;          // A chunks t, t+256
  const int ar1 = (t + 256) >> 3;
  const int br = t >> 4, bc = (t & 15) << 2;           // B row, col base (4 chunks stride 64 rows? no: +256 idx)
  uint4 a_r[2];
  float4 b_r[4];

#define LOADA(IT)                                                             \
  a_r[0] = *(const uint4*)(Ab + (size_t)ar0 * AK + ((IT) << 6) + asl);        \
  a_r[1] = *(const uint4*)(Ab + (size_t)ar1 * AK + ((IT) << 6) + asl);

#define LOADB(IT)                                                             \
  _Pragma("unroll") for (int i = 0; i < 4; ++i) {                             \
    int row = br + (i << 4);                                                  \
    int k = kbase + ((IT) << 6) + bc;                                         \
    const float* src = (MODE == 0)                                            \
        ? W + (size_t)(o0 + row) * SROW + ((k >> 4) << 6) + poff + (k & 15)   \
        : W + (size_t)(o0 + row) * SROW + k;                                  \
    b_r[i] = *(const float4*)src;                                             \
  }

  LOADA(0)
  LOADB(0)

  const int w = t >> 6, lane = t & 63;
  const int wr = w >> 1, wc = w & 1;
  const int frow = lane & 15, fk = (lane >> 4) << 3;
  f32x4 acc[2][2] = {};
  for (int it = 0; it < iters; ++it) {
    __syncthreads();  // readers of previous tile done
    *(uint4*)&As[SWZ(ar0, asl)] = a_r[0];
    *(uint4*)&As[SWZ(ar1, asl)] = a_r[1];
#pragma unroll
    for (int i = 0; i < 4; ++i) {
      half4 h;
      h[0] = (f16)b_r[i].x; h[1] = (f16)b_r[i].y; h[2] = (f16)b_r[i].z; h[3] = (f16)b_r[i].w;
      *(half4*)&Bs[SWZ(br + (i << 4), bc)] = h;
    }
    __syncthreads();
    if (it + 1 < iters) { LOADA(it + 1) LOADB(it + 1) }  // in flight during MFMA
#pragma unroll
    for (int ks = 0; ks < 2; ++ks) {
      const int col = (ks << 5) + fk;
      half8 a0 = *(const half8*)&As[SWZ(wr * 32 + frow, col)];
      half8 a1 = *(const half8*)&As[SWZ(wr * 32 + 16 + frow, col)];
      half8 b0 = *(const half8*)&Bs[SWZ(wc * 32 + frow, col)];
      half8 b1 = *(const half8*)&Bs[SWZ(wc * 32 + 16 + frow, col)];
      acc[0][0] = __builtin_amdgcn_mfma_f32_16x16x32_f16(a0, b0, acc[0][0], 0, 0, 0);
      acc[0][1] = __builtin_amdgcn_mfma_f32_16x16x32_f16(a0, b1, acc[0][1], 0, 0, 0);
      acc[1][0] = __builtin_amdgcn_mfma_f32_16x16x32_f16(a1, b0, acc[1][0], 0, 0, 0);
      acc[1][1] = __builtin_amdgcn_mfma_f32_16x16x32_f16(a1, b1, acc[1][1], 0, 0, 0);
    }
  }
  float* Pb = P + (size_t)(MODE == 0 ? (kc << 2) + s : kc) * 65536;
#pragma unroll
  for (int mi = 0; mi < 2; ++mi)
#pragma unroll
    for (int ni = 0; ni < 2; ++ni)
#pragma unroll
      for (int r = 0; r < 4; ++r) {
        int gm = (m << 6) + wr * 32 + mi * 16 + (lane >> 4) * 4 + r;
        int gn = o0 + wc * 32 + ni * 16 + (lane & 15);
        Pb[(size_t)gm * 512 + gn] = acc[mi][ni][r];
      }
#undef LOADA
#undef LOADB
}

__global__ __launch_bounds__(256) void reduce2(const float* __restrict__ P2,
                                               f16* __restrict__ A3, int nkc) {
  int idx = blockIdx.x * 256 + threadIdx.x;  // 262144 = 4s*128b*512o
  int o = idx & 511, b = (idx >> 9) & 127, s = idx >> 16;
  float v = 0.f;
  for (int kc = 0; kc < nkc; ++kc) v += P2[(size_t)((kc << 2) + s) * 65536 + b * 512 + o];
  v = fmaxf(v * 0.011048543456039805f, 0.f);  // 1/sqrt(8192)
  A3[(size_t)b * 2048 + o * 4 + s] = (f16)v;
}

__global__ __launch_bounds__(256) void out_fused(const float* __restrict__ P3,
                                                 const float* __restrict__ beta,
                                                 float* __restrict__ out, int nkc) {
  const int b = blockIdx.x, t = threadIdx.x;
  float acc = 0.f;
#pragma unroll
  for (int oi = 0; oi < 2; ++oi) {
    int o = (oi << 8) + t;
    float v = 0.f;
    for (int kc = 0; kc < nkc; ++kc) v += P3[(size_t)kc * 65536 + b * 512 + o];
    acc += fmaxf(v * 0.022097086912079608f, 0.f) * beta[o];  // 1/sqrt(2048)
  }
  __shared__ float red[4];
#pragma unroll
  for (int off = 32; off > 0; off >>= 1) acc += __shfl_down(acc, off);
  if ((t & 63) == 0) red[t >> 6] = acc;
  __syncthreads();
  if (t == 0) out[b] = (red[0] + red[1] + red[2] + red[3]) * 0.044194173824159216f;
}

extern "C" void kernel_launch(void* const* d_in, const int* in_sizes, int n_in,
                              void* d_out, int out_size, void* d_ws, size_t ws_size,
                              hipStream_t stream) {
  const float* x    = (const float*)d_in[0];
  const float* w1   = (const float*)d_in[1];
  const float* w2   = (const float*)d_in[2];
  const float* w3   = (const float*)d_in[3];
  const float* beta = (const float*)d_in[4];
  float* out = (float*)d_out;

  // adaptive splitK by workspace size (deterministic given ws_size)
  int nkc2 = 16, nkc3 = 16;
  auto need = [](int k2, int k3) -> size_t {
    return (8ull << 20) + ((size_t)k2 << 20) + (1ull << 19) + ((size_t)k3 << 18);
  };
  while (nkc2 > 4 && need(nkc2, nkc3) > ws_size) nkc2 >>= 1;
  while (nkc3 > 4 && need(nkc2, nkc3) > ws_size) nkc3 >>= 1;

  char* wsb = (char*)d_ws;
  f16*   A2 = (f16*)wsb;                                        // 8 MiB
  float* P2 = (float*)(wsb + (8ull << 20));                     // nkc2 MiB
  f16*   A3 = (f16*)(wsb + (8ull << 20) + ((size_t)nkc2 << 20));    // 0.5 MiB
  float* P3 = (float*)(wsb + (8ull << 20) + ((size_t)nkc2 << 20) + (1ull << 19));  // nkc3/4 MiB

  const int iters2 = 8192 / 64 / nkc2;
  const int iters3 = 2048 / 64 / nkc3;

  l1_mfma<<<dim3(64, 8), 256, 0, stream>>>(x, w1, A2);
  gemm_f16<0><<<nkc2 * 64, 256, 0, stream>>>(A2, w2, P2, iters2);
  reduce2<<<1024, 256, 0, stream>>>(P2, A3, nkc2);
  gemm_f16<1><<<nkc3 * 16, 256, 0, stream>>>(A3, w3, P3, iters3);
  out_fused<<<128, 256, 0, stream>>>(P3, beta, out, nkc3);
}